// Round 15
// baseline (37.103 us; speedup 1.0000x reference)
//
#include <hip/hip_runtime.h>
#include <math.h>

// PolyaTree R15: dual-pipe descent. Dims 0-9 descend via LDS (ds_read/lgkm),
// dims 10-15 via GLOBAL loads of the same 16 KB tables (L1-resident,
// global_load/vmcnt) -- the VMEM pipe was idle in every prior variant.
// Level-outer 16-wide: all 16 loads issue before any wait, so in-order issue
// overlaps both pipes. waves_per_eu(4,4) pins the 128-VGPR config (R8-proven
// no-spill) so the compiler cannot re-serialize for occupancy (R11 failure).
// Tables built by R3's proven bit-exact build_luts (absmax 0.03125).

constexpr int DIMS     = 16;
constexpr int NODES    = 255;
constexpr int INTERNAL = 127;
constexpr int NL       = 10;     // dims via LDS; DIMS-NL dims via global/L1

// --- exact-mirror node interval descent (validated R3..R14) ---
__device__ void node_lohi(const float* s, int j, float& lo, float& hi, float& acc) {
#pragma clang fp contract(off)
    unsigned key = (unsigned)(j + 1);   // 1 then path bits (0 = left)
    int level = 31 - __clz(key);
    lo = 0.0f; hi = 1.0f; acc = 0.0f;
    int i = 0;
    for (int tb = level - 1; tb >= 0; --tb) {
        float b = s[i];
        acc += logf(b);
        float len = hi - lo;
        float split = lo + b * len;     // EXACT mirror of reference (no fma)
        unsigned bit = (key >> tb) & 1u;
        if (bit == 0u) { hi = split; }
        else { lo = split; hi = split + (1.0f - b) * len; }
        i = 2 * i + 1 + (int)bit;
    }
}

__global__ void build_luts(const float* __restrict__ samples, // (16,255)
                           float* __restrict__ ws)            // 4096 floats
{
#pragma clang fp contract(off)
    int t = blockIdx.x * blockDim.x + threadIdx.x;
    if (t >= DIMS * NODES) return;
    int d = t / NODES;
    int j = t - d * NODES;
    const float* s = samples + d * NODES;

    float lo, hi, acc;
    node_lohi(s, j, lo, hi, acc);
    float b = s[j];
    if (j < INTERNAL) {
        ws[d * 128 + j] = lo + b * (hi - lo);                  // split_lut
    } else {
        ws[2048 + d * 128 + (j - INTERNAL)] = acc + logf(b) - logf(hi - lo);
    }
}

__global__ __launch_bounds__(256) __attribute__((amdgpu_waves_per_eu(4, 4)))
void polya_eval(
    const float* __restrict__ x,     // (n,16)
    const float* __restrict__ luts,  // split (16*128) then value (16*128)
    float* __restrict__ out,
    int n)
{
    __shared__ float s_split[NL * 128];   // 5 KB
    __shared__ float s_value[NL * 128];   // 5 KB
    for (int i = threadIdx.x; i < NL * 128; i += 256) {
        s_split[i] = luts[i];
        s_value[i] = luts[2048 + i];
    }
    __syncthreads();
    const float* __restrict__ gsplit = luts;          // dims NL..15 (L1-hit)
    const float* __restrict__ gvalue = luts + 2048;

    const int stride = gridDim.x * 256;
    for (int p = blockIdx.x * 256 + threadIdx.x; p < n; p += stride) {
        const float4* xr = reinterpret_cast<const float4*>(x + (size_t)p * DIMS);
        float4 a = xr[0], b4 = xr[1], c4 = xr[2], e4 = xr[3];
        float xs[DIMS] = {a.x, a.y, a.z, a.w,  b4.x, b4.y, b4.z, b4.w,
                          c4.x, c4.y, c4.z, c4.w,  e4.x, e4.y, e4.z, e4.w};
        int q[DIMS];
#pragma unroll
        for (int d = 0; d < DIMS; ++d) q[d] = 0;

#pragma unroll
        for (int l = 0; l < 7; ++l) {
            float sp[DIMS];
#pragma unroll
            for (int d = 0; d < DIMS; ++d)          // 10 ds_read + 6 global_load
                sp[d] = (d < NL) ? s_split[(d << 7) + q[d]]
                                 : gsplit[(d << 7) + q[d]];
#pragma unroll
            for (int d = 0; d < DIMS; ++d)          // x<=split -> left child
                q[d] = 2 * q[d] + 1 + (int)(xs[d] > sp[d]);
        }
        float acc = 0.0f;
#pragma unroll
        for (int d = 0; d < DIMS; ++d)
            acc += (d < NL) ? s_value[(d << 7) + (q[d] - INTERNAL)]
                            : gvalue[(d << 7) + (q[d] - INTERNAL)];
        out[p] = acc * 0.0625f;   // mean over 16 dims (exact /16)
    }
}

extern "C" void kernel_launch(void* const* d_in, const int* in_sizes, int n_in,
                              void* d_out, int out_size, void* d_ws, size_t ws_size,
                              hipStream_t stream) {
    const float* x       = (const float*)d_in[0];   // (n,16) f32
    const float* samples = (const float*)d_in[1];   // (16,255) f32
    float* out = (float*)d_out;
    const int n = in_sizes[0] / DIMS;
    float* ws = (float*)d_ws;                       // 16 KB tables

    build_luts<<<(DIMS * NODES + 255) / 256, 256, 0, stream>>>(samples, ws);

    int blocks = (n + 255) / 256;
    if (blocks > 2048) blocks = 2048;
    polya_eval<<<blocks, 256, 0, stream>>>(x, ws, out, n);
}